// Round 2
// baseline (234.975 us; speedup 1.0000x reference)
//
#include <hip/hip_runtime.h>
#include <stdint.h>

typedef __attribute__((ext_vector_type(8))) short short8;
typedef __attribute__((ext_vector_type(4))) float f32x4;

#define B_      32
#define C_      3
#define HW_     364
#define D_      1152
#define NPS_    26
#define P_      676      // patches per sample
#define K_      588      // 3*14*14
#define KP_     608      // K padded to multiple of 32
#define KC_     19       // KP_/32 k-chunks
#define MT_     64       // patches per block
#define NT_     384      // cols per block
#define AS_     616      // LDS A row stride (bf16 elems) -> 2-way-only bank conflicts
#define NP_     21632    // B_*P_
#define MBLK_   338      // NP_/MT_
#define NBLK_   3        // D_/NT_
#define NT16_   72       // D_/16

static __device__ __forceinline__ unsigned short f2bf(float x) {
  unsigned u = __float_as_uint(x);
  u += 0x7fffu + ((u >> 16) & 1u);      // round-to-nearest-even
  return (unsigned short)(u >> 16);
}
static __device__ __forceinline__ float bf2f(unsigned short h) {
  return __uint_as_float(((unsigned)h) << 16);
}

// ---- pack conv_w into fragment-major hi/lo bf16, K zero-padded to 608 ----
// layout: idx = ((ntile*19 + kc)*64 + lane)*8 + e
//   value = w[n=ntile*16+(lane&15)][k=kc*32+(lane>>4)*8+e]
__global__ void prep_weights(const float* __restrict__ w,
                             unsigned short* __restrict__ whi,
                             unsigned short* __restrict__ wlo) {
  int idx = blockIdx.x * 256 + threadIdx.x;
  if (idx >= NT16_ * KC_ * 64 * 8) return;
  int e    = idx & 7;
  int lane = (idx >> 3) & 63;
  int t    = idx >> 9;               // ntile*19 + kc
  int kc   = t % KC_;
  int nt   = t / KC_;
  int n = nt * 16 + (lane & 15);
  int k = kc * 32 + (lane >> 4) * 8 + e;
  float x = (k < K_) ? w[n * K_ + k] : 0.0f;
  unsigned short h = f2bf(x);
  float r = x - bf2f(h);
  whi[idx] = h;
  wlo[idx] = f2bf(r);
}

// ---- replicate reference bucketize exactly (fp32, correctly-rounded divides) ----
// Mask dtype is detected at runtime from word0: mask[0,0,0] is always True
// (nbh,nbw >= 13), so word0 == 1 -> int32 mask; 0x01010101 -> byte mask;
// 0x3F800000 -> float mask.
__global__ void prep_pos(const void* __restrict__ maskp, int* __restrict__ pos_ids) {
  const int word0 = ((const int*)maskp)[0];
  int mode;                       // 0 = int32, 1 = byte, 2 = float
  if (word0 == 1) mode = 0;
  else if (word0 == 0x3F800000) mode = 2;
  else mode = 1;

  int idx = blockIdx.x * 256 + threadIdx.x;
  if (idx >= NP_) return;
  const int b = idx / P_;
  const int p = idx - b * P_;
  const int base = b * P_;

  auto get = [&](int i) -> int {
    if (mode == 0) return ((const int*)maskp)[base + i];
    if (mode == 1) return (int)((const unsigned char*)maskp)[base + i];
    return ((const float*)maskp)[base + i] != 0.0f ? 1 : 0;
  };

  int outp = 0;
  if (get(p)) {
    int nbh = 0, nbw = 0;
    #pragma unroll
    for (int r = 0; r < NPS_; ++r) nbh += get(r * NPS_);
    #pragma unroll
    for (int c = 0; c < NPS_; ++c) nbw += get(c);
    const int pr = p / NPS_;
    const int pc = p - pr * NPS_;
    const float eps = 1.0f - 1e-6f;
    const float fh = (float)((double)pr / (double)nbh) * eps;
    const float fw = (float)((double)pc / (double)nbw) * eps;
    int bh = 0, bw = 0;
    #pragma unroll
    for (int k = 1; k < NPS_; ++k) {
      const float bnd = (float)((double)k / (double)NPS_);
      bh += (bnd <= fh) ? 1 : 0;
      bw += (bnd <= fw) ? 1 : 0;
    }
    outp = bh * NPS_ + bw;
  }
  pos_ids[idx] = outp;
}

struct Frags { short8 ah[4]; short8 al[4]; short8 bh[3]; short8 bl[3]; };

__device__ __forceinline__ void load_frags(Frags& f, int kc, int l15, int lk8,
                                           int ntbase, int lane,
                                           const unsigned short* Ahi_,
                                           const unsigned short* Alo_,
                                           const unsigned short* __restrict__ whi,
                                           const unsigned short* __restrict__ wlo) {
  const int ko = kc * 32 + lk8;
  #pragma unroll
  for (int mi = 0; mi < 4; ++mi) {
    f.ah[mi] = *(const short8*)&Ahi_[(mi * 16 + l15) * AS_ + ko];
    f.al[mi] = *(const short8*)&Alo_[(mi * 16 + l15) * AS_ + ko];
  }
  #pragma unroll
  for (int ni = 0; ni < 3; ++ni) {
    const int off = (((ntbase + ni) * KC_ + kc) * 64 + lane) * 8;
    f.bh[ni] = *(const short8*)(whi + off);
    f.bl[ni] = *(const short8*)(wlo + off);
  }
}

__device__ __forceinline__ void mfma_frags(f32x4 acc[4][3], const Frags& f) {
  #pragma unroll
  for (int mi = 0; mi < 4; ++mi)
    #pragma unroll
    for (int ni = 0; ni < 3; ++ni)
      acc[mi][ni] = __builtin_amdgcn_mfma_f32_16x16x32_bf16(f.ah[mi], f.bh[ni], acc[mi][ni], 0, 0, 0);
  #pragma unroll
  for (int mi = 0; mi < 4; ++mi)
    #pragma unroll
    for (int ni = 0; ni < 3; ++ni)
      acc[mi][ni] = __builtin_amdgcn_mfma_f32_16x16x32_bf16(f.ah[mi], f.bl[ni], acc[mi][ni], 0, 0, 0);
  #pragma unroll
  for (int mi = 0; mi < 4; ++mi)
    #pragma unroll
    for (int ni = 0; ni < 3; ++ni)
      acc[mi][ni] = __builtin_amdgcn_mfma_f32_16x16x32_bf16(f.al[mi], f.bh[ni], acc[mi][ni], 0, 0, 0);
}

__global__ __launch_bounds__(512, 2)
void fused_embed(const float* __restrict__ pix,
                 const unsigned short* __restrict__ whi,
                 const unsigned short* __restrict__ wlo,
                 const float* __restrict__ bias,
                 const float* __restrict__ pos_emb,
                 const int* __restrict__ pos_ids,
                 float* __restrict__ out) {
  __shared__ __align__(16) unsigned short Ahi[MT_ * AS_];
  __shared__ __align__(16) unsigned short Alo[MT_ * AS_];

  const int bid = blockIdx.x;
  const int mb  = bid / NBLK_;
  const int nb  = bid - mb * NBLK_;
  const int P0  = mb * MT_;
  const int tid = threadIdx.x;

  // ---- stage A strip: 64 patches x K(588) as hi/lo bf16 in LDS ----
  // task = s*64 + p, s = c*14 + rr  -> consecutive lanes read adjacent 14-float runs
  for (int task = tid; task < 42 * 64; task += 512) {
    const int s  = task >> 6;
    const int p  = task & 63;
    const int c  = s / 14;
    const int rr = s - c * 14;
    const int patch = P0 + p;
    const int b  = patch / P_;
    const int pp = patch - b * P_;
    const int pr = pp / NPS_;
    const int pc = pp - pr * NPS_;
    const float* src = pix + ((size_t)(b * C_ + c) * HW_ + pr * 14 + rr) * HW_ + pc * 14;
    const int kb = c * 196 + rr * 14;
    unsigned short* dh = &Ahi[p * AS_ + kb];
    unsigned short* dl = &Alo[p * AS_ + kb];
    #pragma unroll
    for (int j = 0; j < 14; j += 2) {
      float x0 = src[j], x1 = src[j + 1];
      unsigned short h0 = f2bf(x0), h1 = f2bf(x1);
      unsigned short l0 = f2bf(x0 - bf2f(h0)), l1 = f2bf(x1 - bf2f(h1));
      *(unsigned*)(dh + j) = (unsigned)h0 | ((unsigned)h1 << 16);
      *(unsigned*)(dl + j) = (unsigned)l0 | ((unsigned)l1 << 16);
    }
  }
  // zero K-pad region [588, 616)
  for (int i = tid; i < MT_ * 14; i += 512) {
    const int p = i / 14;
    const int k = K_ + (i - p * 14) * 2;
    *(unsigned*)(&Ahi[p * AS_ + k]) = 0u;
    *(unsigned*)(&Alo[p * AS_ + k]) = 0u;
  }
  __syncthreads();

  const int lane = tid & 63;
  const int wid  = tid >> 6;            // 0..7, each wave owns 48 cols
  const int l15  = lane & 15;
  const int lk8  = (lane >> 4) << 3;
  const int ntbase = nb * 24 + wid * 3; // global 16-col tile base

  f32x4 acc[4][3];
  #pragma unroll
  for (int mi = 0; mi < 4; ++mi)
    #pragma unroll
    for (int ni = 0; ni < 3; ++ni)
      acc[mi][ni] = (f32x4)0.0f;

  // ---- K loop, 2-stage software pipeline, no barriers ----
  Frags f0, f1;
  load_frags(f0, 0, l15, lk8, ntbase, lane, Ahi, Alo, whi, wlo);
  #pragma unroll 1
  for (int kc = 0; kc + 2 < KC_; kc += 2) {
    load_frags(f1, kc + 1, l15, lk8, ntbase, lane, Ahi, Alo, whi, wlo);
    mfma_frags(acc, f0);
    load_frags(f0, kc + 2, l15, lk8, ntbase, lane, Ahi, Alo, whi, wlo);
    mfma_frags(acc, f1);
  }
  mfma_frags(acc, f0);   // kc = 18

  // ---- epilogue: + bias + pos_emb[pos_ids] ----
  const int colb = nb * NT_ + wid * 48;
  float cb[3];
  #pragma unroll
  for (int ni = 0; ni < 3; ++ni) cb[ni] = bias[colb + ni * 16 + l15];
  const int r4 = (lane >> 4) * 4;
  #pragma unroll
  for (int mi = 0; mi < 4; ++mi) {
    #pragma unroll
    for (int r = 0; r < 4; ++r) {
      const int patch = P0 + mi * 16 + r4 + r;
      const int pid = pos_ids[patch];
      const float* pe = pos_emb + (size_t)pid * D_;
      float* po = out + (size_t)patch * D_;
      #pragma unroll
      for (int ni = 0; ni < 3; ++ni) {
        const int col = colb + ni * 16 + l15;
        po[col] = acc[mi][ni][r] + cb[ni] + pe[col];
      }
    }
  }
}

extern "C" void kernel_launch(void* const* d_in, const int* in_sizes, int n_in,
                              void* d_out, int out_size, void* d_ws, size_t ws_size,
                              hipStream_t stream) {
  const float* pix            = (const float*)d_in[0];
  const void* mask            = (const void*)d_in[1];
  const float* conv_w         = (const float*)d_in[2];
  const float* conv_b         = (const float*)d_in[3];
  const float* pos_emb        = (const float*)d_in[4];
  float* out                  = (float*)d_out;

  char* ws = (char*)d_ws;
  unsigned short* whi = (unsigned short*)ws;                 // 1,400,832 B
  unsigned short* wlo = (unsigned short*)(ws + 1400832);     // 1,400,832 B
  int* pos_ids        = (int*)(ws + 2801664);                // 86,528 B  (total ~2.9 MB)

  prep_weights<<<(NT16_ * KC_ * 64 * 8 + 255) / 256, 256, 0, stream>>>(conv_w, whi, wlo);
  prep_pos<<<(NP_ + 255) / 256, 256, 0, stream>>>(mask, pos_ids);
  fused_embed<<<MBLK_ * NBLK_, 512, 0, stream>>>(pix, whi, wlo, conv_b, pos_emb, pos_ids, out);
}

// Round 5
// 186.513 us; speedup vs baseline: 1.2598x; 1.2598x over previous
//
#include <hip/hip_runtime.h>
#include <stdint.h>

typedef __attribute__((ext_vector_type(8))) short short8;
typedef __attribute__((ext_vector_type(4))) float f32x4;

#define B_      32
#define C_      3
#define HW_     364
#define D_      1152
#define NPS_    26
#define P_      676      // patches per sample
#define K_      588      // 3*14*14
#define KP_     608      // K padded to multiple of 32
#define KC_     19       // KP_/32 k-chunks
#define MT_     64       // patches per block
#define NT_     384      // cols per block
#define AS_     616      // LDS A row stride (bf16 elems) -> 2-way-only bank conflicts (free, m136)
#define NP_     21632    // B_*P_
#define MBLK_   338      // NP_/MT_
#define NBLK_   3        // D_/NT_
#define NT16_   72       // D_/16

static __device__ __forceinline__ unsigned short f2bf(float x) {
  unsigned u = __float_as_uint(x);
  u += 0x7fffu + ((u >> 16) & 1u);      // round-to-nearest-even
  return (unsigned short)(u >> 16);
}

// ---- pack conv_w into fragment-major bf16, K zero-padded to 608 ----
// layout: idx = ((ntile*19 + kc)*64 + lane)*8 + e
//   value = w[n=ntile*16+(lane&15)][k=kc*32+(lane>>4)*8+e]
__global__ void prep_weights(const float* __restrict__ w,
                             unsigned short* __restrict__ whi) {
  int idx = blockIdx.x * 256 + threadIdx.x;
  if (idx >= NT16_ * KC_ * 64 * 8) return;
  int e    = idx & 7;
  int lane = (idx >> 3) & 63;
  int t    = idx >> 9;               // ntile*19 + kc
  int kc   = t % KC_;
  int nt   = t / KC_;
  int n = nt * 16 + (lane & 15);
  int k = kc * 32 + (lane >> 4) * 8 + e;
  float x = (k < K_) ? w[n * K_ + k] : 0.0f;
  whi[idx] = f2bf(x);
}

// ---- replicate reference bucketize exactly (fp32, correctly-rounded divides) ----
// Mask dtype detected from word0 (mask[0,0,0] is always True):
// 1 -> int32, 0x3F800000 -> float, else packed bytes.
__global__ void prep_pos(const void* __restrict__ maskp, int* __restrict__ pos_ids) {
  const int word0 = ((const int*)maskp)[0];
  int mode;                       // 0 = int32, 1 = byte, 2 = float
  if (word0 == 1) mode = 0;
  else if (word0 == 0x3F800000) mode = 2;
  else mode = 1;

  int idx = blockIdx.x * 256 + threadIdx.x;
  if (idx >= NP_) return;
  const int b = idx / P_;
  const int p = idx - b * P_;
  const int base = b * P_;

  auto get = [&](int i) -> int {
    if (mode == 0) return ((const int*)maskp)[base + i];
    if (mode == 1) return (int)((const unsigned char*)maskp)[base + i];
    return ((const float*)maskp)[base + i] != 0.0f ? 1 : 0;
  };

  int outp = 0;
  if (get(p)) {
    int nbh = 0, nbw = 0;
    #pragma unroll
    for (int r = 0; r < NPS_; ++r) nbh += get(r * NPS_);
    #pragma unroll
    for (int c = 0; c < NPS_; ++c) nbw += get(c);
    const int pr = p / NPS_;
    const int pc = p - pr * NPS_;
    const float eps = 1.0f - 1e-6f;
    const float fh = (float)((double)pr / (double)nbh) * eps;
    const float fw = (float)((double)pc / (double)nbw) * eps;
    int bh = 0, bw = 0;
    #pragma unroll
    for (int k = 1; k < NPS_; ++k) {
      const float bnd = (float)((double)k / (double)NPS_);
      bh += (bnd <= fh) ? 1 : 0;
      bw += (bnd <= fw) ? 1 : 0;
    }
    outp = bh * NPS_ + bw;
  }
  pos_ids[idx] = outp;
}

struct Frags { short8 ah[4]; short8 bh[3]; };

__device__ __forceinline__ void load_frags(Frags& f, int kc, int l15, int lk8,
                                           int ntbase, int lane,
                                           const unsigned short* Ahi_,
                                           const unsigned short* __restrict__ whi) {
  const int ko = kc * 32 + lk8;
  #pragma unroll
  for (int mi = 0; mi < 4; ++mi)
    f.ah[mi] = *(const short8*)&Ahi_[(mi * 16 + l15) * AS_ + ko];
  #pragma unroll
  for (int ni = 0; ni < 3; ++ni) {
    const int off = (((ntbase + ni) * KC_ + kc) * 64 + lane) * 8;
    f.bh[ni] = *(const short8*)(whi + off);
  }
}

__device__ __forceinline__ void mfma_frags(f32x4 acc[4][3], const Frags& f) {
  #pragma unroll
  for (int mi = 0; mi < 4; ++mi)
    #pragma unroll
    for (int ni = 0; ni < 3; ++ni)
      acc[mi][ni] = __builtin_amdgcn_mfma_f32_16x16x32_bf16(f.ah[mi], f.bh[ni], acc[mi][ni], 0, 0, 0);
}

__global__ __launch_bounds__(512, 4)   // 4 waves/EU -> 2 blocks/CU (LDS 78,848 B x2 fits 160K)
void fused_embed(const float* __restrict__ pix,
                 const unsigned short* __restrict__ whi,
                 const float* __restrict__ bias,
                 const float* __restrict__ pos_emb,
                 const int* __restrict__ pos_ids,
                 float* __restrict__ out) {
  __shared__ __align__(16) unsigned short Ahi[MT_ * AS_];

  const int bid = blockIdx.x;
  const int mb  = bid / NBLK_;
  const int nb  = bid - mb * NBLK_;
  const int P0  = mb * MT_;
  const int tid = threadIdx.x;

  // ---- stage A strip: 64 patches x K(588) as bf16 in LDS ----
  // task = s*64 + p, s = c*14 + rr  -> wave reads a contiguous 3.5KB span per task row
  for (int task = tid; task < 42 * 64; task += 512) {
    const int s  = task >> 6;
    const int p  = task & 63;
    const int c  = s / 14;
    const int rr = s - c * 14;
    const int patch = P0 + p;
    const int b  = patch / P_;
    const int pp = patch - b * P_;
    const int pr = pp / NPS_;
    const int pc = pp - pr * NPS_;
    const float* src = pix + ((size_t)(b * C_ + c) * HW_ + pr * 14 + rr) * HW_ + pc * 14;
    const int kb = c * 196 + rr * 14;
    unsigned short* dh = &Ahi[p * AS_ + kb];
    #pragma unroll
    for (int j = 0; j < 14; j += 2) {
      float x0 = src[j], x1 = src[j + 1];
      *(unsigned*)(dh + j) = (unsigned)f2bf(x0) | ((unsigned)f2bf(x1) << 16);
    }
  }
  // zero K-pad region [588, 616)
  for (int i = tid; i < MT_ * 14; i += 512) {
    const int p = i / 14;
    const int k = K_ + (i - p * 14) * 2;
    *(unsigned*)(&Ahi[p * AS_ + k]) = 0u;
  }
  __syncthreads();

  const int lane = tid & 63;
  const int wid  = tid >> 6;            // 0..7, each wave owns 48 cols
  const int l15  = lane & 15;
  const int lk8  = (lane >> 4) << 3;
  const int ntbase = nb * 24 + wid * 3; // global 16-col tile base

  f32x4 acc[4][3];
  #pragma unroll
  for (int mi = 0; mi < 4; ++mi)
    #pragma unroll
    for (int ni = 0; ni < 3; ++ni)
      acc[mi][ni] = (f32x4)0.0f;

  // ---- K loop, 2-stage software pipeline, no barriers ----
  Frags f0, f1;
  load_frags(f0, 0, l15, lk8, ntbase, lane, Ahi, whi);
  #pragma unroll 1
  for (int kc = 0; kc + 2 < KC_; kc += 2) {
    load_frags(f1, kc + 1, l15, lk8, ntbase, lane, Ahi, whi);
    mfma_frags(acc, f0);
    load_frags(f0, kc + 2, l15, lk8, ntbase, lane, Ahi, whi);
    mfma_frags(acc, f1);
  }
  mfma_frags(acc, f0);   // kc = 18

  // ---- epilogue: + bias + pos_emb[pos_ids] ----
  const int colb = nb * NT_ + wid * 48;
  float cb[3];
  #pragma unroll
  for (int ni = 0; ni < 3; ++ni) cb[ni] = bias[colb + ni * 16 + l15];
  const int r4 = (lane >> 4) * 4;
  #pragma unroll
  for (int mi = 0; mi < 4; ++mi) {
    #pragma unroll
    for (int r = 0; r < 4; ++r) {
      const int patch = P0 + mi * 16 + r4 + r;
      const int pid = pos_ids[patch];
      const float* pe = pos_emb + (size_t)pid * D_;
      float* po = out + (size_t)patch * D_;
      #pragma unroll
      for (int ni = 0; ni < 3; ++ni) {
        const int col = colb + ni * 16 + l15;
        po[col] = acc[mi][ni][r] + cb[ni] + pe[col];
      }
    }
  }
}

extern "C" void kernel_launch(void* const* d_in, const int* in_sizes, int n_in,
                              void* d_out, int out_size, void* d_ws, size_t ws_size,
                              hipStream_t stream) {
  const float* pix            = (const float*)d_in[0];
  const void* mask            = (const void*)d_in[1];
  const float* conv_w         = (const float*)d_in[2];
  const float* conv_b         = (const float*)d_in[3];
  const float* pos_emb        = (const float*)d_in[4];
  float* out                  = (float*)d_out;

  char* ws = (char*)d_ws;
  unsigned short* whi = (unsigned short*)ws;                 // 1,400,832 B
  int* pos_ids        = (int*)(ws + 1400832);                // 86,528 B

  prep_weights<<<(NT16_ * KC_ * 64 * 8 + 255) / 256, 256, 0, stream>>>(conv_w, whi);
  prep_pos<<<(NP_ + 255) / 256, 256, 0, stream>>>(mask, pos_ids);
  fused_embed<<<MBLK_ * NBLK_, 512, 0, stream>>>(pix, whi, conv_b, pos_emb, pos_ids, out);
}